// Round 2
// baseline (15690.231 us; speedup 1.0000x reference)
//
#include <hip/hip_runtime.h>
#include <cstdint>
#include <cstddef>

typedef unsigned short u16;
typedef __bf16 bf16_t;
typedef bf16_t bf16x8 __attribute__((ext_vector_type(8)));
typedef float f32x4 __attribute__((ext_vector_type(4)));

static constexpr int HID    = 512;
static constexpr int BATCH  = 1024;
static constexpr int NSTEPS = 95;   // T + future - 1 = 64 + 31
static constexpr int T_OBS  = 64;
static constexpr int OUTW   = 190;  // 2 * NSTEPS

// ---------- helpers ----------
__device__ __forceinline__ u16 f2bf(float x) {
  union { float f; uint32_t u; } c; c.f = x;
  uint32_t r = c.u + 0x7fffu + ((c.u >> 16) & 1u);   // round-to-nearest-even
  return (u16)(r >> 16);
}
__device__ __forceinline__ float bf2f(u16 h) {
  union { uint32_t u; float f; } c; c.u = ((uint32_t)h) << 16;
  return c.f;
}
__device__ __forceinline__ float sigm(float x) { return 1.f / (1.f + __expf(-x)); }
__device__ __forceinline__ float tanh_fast(float x) {
  float ax = fabsf(x);
  float t  = __expf(-2.f * ax);
  float r  = (1.f - t) / (1.f + t);
  return x < 0.f ? -r : r;
}

// ---------- weight prep (gate-interleaved column order) ----------
// col n = 4*h + g  <->  original row r = g*512 + h
__global__ void prep_bt1(const float* __restrict__ Whh1, u16* __restrict__ Bt1) {
  int idx = blockIdx.x * 256 + threadIdx.x;       // 2048*1024
  int n = idx >> 10, kk = idx & 1023;
  int r = (n & 3) * HID + (n >> 2);
  int k = kk & 511;
  float v = Whh1[r * HID + k];
  u16 hi = f2bf(v);
  Bt1[idx] = (kk < 512) ? hi : f2bf(v - bf2f(hi));
}
__global__ void prep_bt2(const float* __restrict__ Wih2, const float* __restrict__ Whh2,
                         u16* __restrict__ Bt2) {
  int idx = blockIdx.x * 256 + threadIdx.x;       // 2048*2048
  int n = idx >> 11, kk = idx & 2047;
  int r = (n & 3) * HID + (n >> 2);
  int k = kk & 1023;
  float v = (k < 512) ? Wih2[r * HID + k] : Whh2[r * HID + (k - 512)];
  u16 hi = f2bf(v);
  Bt2[idx] = (kk < 1024) ? hi : f2bf(v - bf2f(hi));
}
__global__ void prep_small(const float* __restrict__ b1, const float* __restrict__ b2,
                           const float* __restrict__ Wih1,
                           float* __restrict__ b1p, float* __restrict__ b2p,
                           float* __restrict__ w1p) {
  int n = blockIdx.x * 256 + threadIdx.x;
  if (n >= 2048) return;
  int r = (n & 3) * HID + (n >> 2);
  b1p[n] = b1[r];
  b2p[n] = b2[r];
  w1p[2 * n + 0] = Wih1[2 * r + 0];
  w1p[2 * n + 1] = Wih1[2 * r + 1];
}
__global__ void init_out(const float* __restrict__ bl, float* __restrict__ out) {
  int i = blockIdx.x * 256 + threadIdx.x;
  if (i < BATCH * OUTW) out[i] = bl[i & 1];
}

// ---------- fused gate-GEMM + LSTM cell (+ optional out-projection) ----------
struct GemmArgs {
  const u16* achunk[6];             // A panels per 512-wide K chunk
  int boff[6];                      // B column offset per chunk
  const u16* Bt;  int bstride;      // bf16 weight panel, row stride in elements
  const float* bias;                // reordered bias [2048]
  const float* xptr; int xstride;   // layer-1 input (2 floats/row), else null
  const float* wih;                 // reordered Wih1 [2048][2], else null
  float* Cst;                       // cell state [1024][512], RMW
  u16* Hh; u16* Hl;                 // output h hi/lo [1024][512]
  const float* wl;                  // Wl [2][512] original order, else null
  float* oacc;                      // out + 2t (atomic accumulate), else null
  int nch;                          // 3 (layer1) or 6 (layer2)
  int hasx;
};

// BM=BN=64, BK=128. LDS: A[64][136] + B[64][136] bf16 = 34816 B.
__device__ __forceinline__ void run_gemm(const GemmArgs& a, int mt, int nt, char* smem) {
  u16* As = (u16*)smem;
  u16* Bs = (u16*)(smem + 64 * 136 * 2);

  const int tid = threadIdx.x;
  const int wid = tid >> 6, lane = tid & 63;
  const int wm = wid >> 1, wn = wid & 1;
  const int r0 = tid >> 4;           // 0..15
  const int sl = tid & 15;           // 16B slot in a 256B row

  f32x4 acc[2][2] = {};
  const int TOT = a.nch * 4;         // K-steps of 128

  uint4 pa[4], pb[4];
  auto loadT = [&](int ks, uint4* va, uint4* vb) {
    int c = ks >> 2, k0 = (ks & 3) * 128;
    const u16* Ap = a.achunk[c] + (size_t)(mt * 64) * HID + k0 + sl * 8;
    const u16* Bp = a.Bt + (size_t)(nt * 64) * a.bstride + a.boff[c] + k0 + sl * 8;
#pragma unroll
    for (int i = 0; i < 4; ++i) {
      va[i] = *(const uint4*)(Ap + (size_t)(r0 + 16 * i) * HID);
      vb[i] = *(const uint4*)(Bp + (size_t)(r0 + 16 * i) * a.bstride);
    }
  };
  loadT(0, pa, pb);

  for (int ks = 0; ks < TOT; ++ks) {
    __syncthreads();
#pragma unroll
    for (int i = 0; i < 4; ++i) {
      *(uint4*)(As + (r0 + 16 * i) * 136 + sl * 8) = pa[i];
      *(uint4*)(Bs + (r0 + 16 * i) * 136 + sl * 8) = pb[i];
    }
    __syncthreads();
    int ksn = (ks + 1 < TOT) ? ks + 1 : ks;        // redundant last prefetch
    uint4 na[4], nb[4];
    loadT(ksn, na, nb);
#pragma unroll
    for (int kk = 0; kk < 4; ++kk) {
      const int ko = kk * 32 + (lane >> 4) * 8;
      bf16x8 a0 = *(const bf16x8*)(As + (wm * 32 +  0 + (lane & 15)) * 136 + ko);
      bf16x8 a1 = *(const bf16x8*)(As + (wm * 32 + 16 + (lane & 15)) * 136 + ko);
      bf16x8 b0 = *(const bf16x8*)(Bs + (wn * 32 +  0 + (lane & 15)) * 136 + ko);
      bf16x8 b1 = *(const bf16x8*)(Bs + (wn * 32 + 16 + (lane & 15)) * 136 + ko);
      acc[0][0] = __builtin_amdgcn_mfma_f32_16x16x32_bf16(a0, b0, acc[0][0], 0, 0, 0);
      acc[0][1] = __builtin_amdgcn_mfma_f32_16x16x32_bf16(a0, b1, acc[0][1], 0, 0, 0);
      acc[1][0] = __builtin_amdgcn_mfma_f32_16x16x32_bf16(a1, b0, acc[1][0], 0, 0, 0);
      acc[1][1] = __builtin_amdgcn_mfma_f32_16x16x32_bf16(a1, b1, acc[1][1], 0, 0, 0);
    }
#pragma unroll
    for (int i = 0; i < 4; ++i) { pa[i] = na[i]; pb[i] = nb[i]; }
  }

  // ---- epilogue ----
  __syncthreads();
  float* Cl = (float*)smem;                        // [64][65]
#pragma unroll
  for (int mi = 0; mi < 2; ++mi)
#pragma unroll
    for (int ni = 0; ni < 2; ++ni)
#pragma unroll
      for (int r = 0; r < 4; ++r) {
        int row = wm * 32 + mi * 16 + (lane >> 4) * 4 + r;
        int col = wn * 32 + ni * 16 + (lane & 15);
        Cl[row * 65 + col] = acc[mi][ni][r];
      }
  __syncthreads();

  const int mg0 = mt * 64;
  const int hg0 = nt * 16;
#pragma unroll
  for (int q = 0; q < 4; ++q) {
    int idx = q * 256 + tid;          // 64 rows x 16 h
    int m = idx >> 4, hl = idx & 15;
    int mg = mg0 + m, hg = hg0 + hl;
    int nb = hg * 4;
    float g0 = Cl[m * 65 + hl * 4 + 0] + a.bias[nb + 0];
    float g1 = Cl[m * 65 + hl * 4 + 1] + a.bias[nb + 1];
    float g2 = Cl[m * 65 + hl * 4 + 2] + a.bias[nb + 2];
    float g3 = Cl[m * 65 + hl * 4 + 3] + a.bias[nb + 3];
    if (a.hasx) {
      float x0 = a.xptr[(size_t)mg * a.xstride + 0];
      float x1 = a.xptr[(size_t)mg * a.xstride + 1];
      g0 += x0 * a.wih[(nb + 0) * 2] + x1 * a.wih[(nb + 0) * 2 + 1];
      g1 += x0 * a.wih[(nb + 1) * 2] + x1 * a.wih[(nb + 1) * 2 + 1];
      g2 += x0 * a.wih[(nb + 2) * 2] + x1 * a.wih[(nb + 2) * 2 + 1];
      g3 += x0 * a.wih[(nb + 3) * 2] + x1 * a.wih[(nb + 3) * 2 + 1];
    }
    float ig = sigm(g0), fg = sigm(g1), gg = tanh_fast(g2), og = sigm(g3);
    float cp = a.Cst[(size_t)mg * HID + hg];
    float cn = fg * cp + ig * gg;
    a.Cst[(size_t)mg * HID + hg] = cn;
    float hn = og * tanh_fast(cn);
    u16 hi = f2bf(hn);
    a.Hh[(size_t)mg * HID + hg] = hi;
    a.Hl[(size_t)mg * HID + hg] = f2bf(hn - bf2f(hi));
    if (a.wl) {                       // fused output projection
      float s0 = hn * a.wl[hg];
      float s1 = hn * a.wl[HID + hg];
      s0 += __shfl_down(s0, 8); s1 += __shfl_down(s1, 8);
      s0 += __shfl_down(s0, 4); s1 += __shfl_down(s1, 4);
      s0 += __shfl_down(s0, 2); s1 += __shfl_down(s1, 2);
      s0 += __shfl_down(s0, 1); s1 += __shfl_down(s1, 1);
      if (hl == 0) {
        unsafeAtomicAdd(&a.oacc[(size_t)mg * OUTW + 0], s0);
        unsafeAtomicAdd(&a.oacc[(size_t)mg * OUTW + 1], s1);
      }
    }
  }
}

// XCD-pinned tile mapping: xcd = bid&7 owns nt in [xcd*4, xcd*4+4).
// grid 512: one GEMM (ga). grid 1024: j<64 -> ga (L2 of step t), j>=64 -> gb (L1 of t+1).
__global__ __launch_bounds__(256, 2) void lstm_step(GemmArgs ga, GemmArgs gb) {
  __shared__ __align__(16) char smem[34816];
  int bid = blockIdx.x;
  int x = bid & 7, j = bid >> 3;
  int jj = j & 63;
  int nt = x * 4 + (jj & 3);
  int mt = jj >> 2;
  if (j < 64) run_gemm(ga, mt, nt, smem);
  else        run_gemm(gb, mt, nt, smem);
}

// ---------- host ----------
extern "C" void kernel_launch(void* const* d_in, const int* in_sizes, int n_in,
                              void* d_out, int out_size, void* d_ws, size_t ws_size,
                              hipStream_t stream) {
  const float* x    = (const float*)d_in[0];
  const float* Wih1 = (const float*)d_in[1];
  const float* Whh1 = (const float*)d_in[2];
  const float* b1   = (const float*)d_in[3];
  const float* Wih2 = (const float*)d_in[4];
  const float* Whh2 = (const float*)d_in[5];
  const float* b2   = (const float*)d_in[6];
  const float* bl   = (const float*)d_in[8];
  const float* Wl   = (const float*)d_in[7];
  float* out = (float*)d_out;
  (void)in_sizes; (void)n_in; (void)out_size; (void)ws_size;

  char* p = (char*)d_ws;
  auto alloc = [&](size_t bytes) -> char* {
    char* r = p; p += (bytes + 255) & ~(size_t)255; return r;
  };
  u16* Bt1 = (u16*)alloc((size_t)2048 * 1024 * 2);   // 4 MB
  u16* Bt2 = (u16*)alloc((size_t)2048 * 2048 * 2);   // 8 MB
  char* state0 = p;
  u16* Hb[8];                                        // H1h[2],H1l[2],H2h[2],H2l[2]
  for (int i = 0; i < 8; ++i) Hb[i] = (u16*)alloc((size_t)BATCH * HID * 2);
  float* C1 = (float*)alloc((size_t)BATCH * HID * 4);
  float* C2 = (float*)alloc((size_t)BATCH * HID * 4);
  size_t state_bytes = (size_t)(p - state0);
  float* b1p = (float*)alloc(2048 * 4);
  float* b2p = (float*)alloc(2048 * 4);
  float* w1p = (float*)alloc(2048 * 2 * 4);

  hipMemsetAsync(state0, 0, state_bytes, stream);    // h,c = 0
  init_out<<<(BATCH * OUTW + 255) / 256, 256, 0, stream>>>(bl, out);
  prep_bt1<<<8192, 256, 0, stream>>>(Whh1, Bt1);
  prep_bt2<<<16384, 256, 0, stream>>>(Wih2, Whh2, Bt2);
  prep_small<<<8, 256, 0, stream>>>(b1, b2, Wih1, b1p, b2p, w1p);

  auto mkL1 = [&](int t) -> GemmArgs {
    int par = t & 1, prev = par ^ 1;
    GemmArgs a{};
    a.achunk[0] = Hb[0 + prev];      // H1h_p x Bh
    a.achunk[1] = Hb[2 + prev];      // H1l_p x Bh
    a.achunk[2] = Hb[0 + prev];      // H1h_p x Bl
    a.boff[0] = 0; a.boff[1] = 0; a.boff[2] = 512;
    a.Bt = Bt1; a.bstride = 1024; a.bias = b1p;
    a.xptr = (t < T_OBS) ? (x + 2 * t) : (out + 2 * (t - 1));
    a.xstride = (t < T_OBS) ? (2 * T_OBS) : OUTW;
    a.wih = w1p; a.Cst = C1;
    a.Hh = Hb[0 + par]; a.Hl = Hb[2 + par];
    a.wl = nullptr; a.oacc = nullptr;
    a.nch = 3; a.hasx = 1;
    return a;
  };
  auto mkL2 = [&](int t) -> GemmArgs {
    int par = t & 1, prev = par ^ 1;
    GemmArgs a{};
    a.achunk[0] = Hb[0 + par];       // H1h x Bh[0:512]
    a.achunk[1] = Hb[4 + prev];      // H2h_p x Bh[512:1024]
    a.achunk[2] = Hb[2 + par];       // H1l x Bh[0:512]
    a.achunk[3] = Hb[6 + prev];      // H2l_p x Bh[512:1024]
    a.achunk[4] = Hb[0 + par];       // H1h x Bl[0:512]
    a.achunk[5] = Hb[4 + prev];      // H2h_p x Bl[512:1024]
    a.boff[0] = 0; a.boff[1] = 512; a.boff[2] = 0;
    a.boff[3] = 512; a.boff[4] = 1024; a.boff[5] = 1536;
    a.Bt = Bt2; a.bstride = 2048; a.bias = b2p;
    a.xptr = nullptr; a.xstride = 0; a.wih = nullptr;
    a.Cst = C2;
    a.Hh = Hb[4 + par]; a.Hl = Hb[6 + par];
    a.wl = Wl; a.oacc = out + 2 * t;
    a.nch = 6; a.hasx = 0;
    return a;
  };

  GemmArgs dummy{};

  // step 0 layer 1
  lstm_step<<<512, 256, 0, stream>>>(mkL1(0), dummy);
  // observed steps: fuse L2(t) with L1(t+1)  (independent GEMMs)
  for (int t = 0; t < T_OBS - 1; ++t)
    lstm_step<<<1024, 256, 0, stream>>>(mkL2(t), mkL1(t + 1));
  // last observed L2 (writes out[63])
  lstm_step<<<512, 256, 0, stream>>>(mkL2(T_OBS - 1), dummy);
  // future steps: strict chain L1 -> L2(+proj) -> L1 ...
  for (int t = T_OBS; t < NSTEPS; ++t) {
    lstm_step<<<512, 256, 0, stream>>>(mkL1(t), dummy);
    lstm_step<<<512, 256, 0, stream>>>(mkL2(t), dummy);
  }
}

// Round 3
// 15240.833 us; speedup vs baseline: 1.0295x; 1.0295x over previous
//
#include <hip/hip_runtime.h>
#include <cstdint>
#include <cstddef>

typedef unsigned short u16;
typedef __bf16 bf16_t;
typedef bf16_t bf16x8 __attribute__((ext_vector_type(8)));
typedef float f32x4 __attribute__((ext_vector_type(4)));

static constexpr int HID    = 512;
static constexpr int BATCH  = 1024;
static constexpr int NSTEPS = 95;   // T + future - 1 = 64 + 31
static constexpr int T_OBS  = 64;
static constexpr int OUTW   = 190;  // 2 * NSTEPS

// ---------- helpers ----------
__device__ __forceinline__ u16 f2bf(float x) {
  union { float f; uint32_t u; } c; c.f = x;
  uint32_t r = c.u + 0x7fffu + ((c.u >> 16) & 1u);   // RNE
  return (u16)(r >> 16);
}
__device__ __forceinline__ float bf2f(u16 h) {
  union { uint32_t u; float f; } c; c.u = ((uint32_t)h) << 16;
  return c.f;
}
__device__ __forceinline__ float sigm(float x) { return 1.f / (1.f + __expf(-x)); }
__device__ __forceinline__ float tanh_fast(float x) {
  float ax = fabsf(x);
  float t  = __expf(-2.f * ax);
  float r  = (1.f - t) / (1.f + t);
  return x < 0.f ? -r : r;
}

// ---------- weight prep (gate-interleaved column order) ----------
// col n = 4*h + g  <->  original row r = g*512 + h
__global__ void prep_bt1(const float* __restrict__ Whh1, u16* __restrict__ Bt1) {
  int idx = blockIdx.x * 256 + threadIdx.x;       // 2048*1024
  int n = idx >> 10, kk = idx & 1023;
  int r = (n & 3) * HID + (n >> 2);
  int k = kk & 511;
  float v = Whh1[r * HID + k];
  u16 hi = f2bf(v);
  Bt1[idx] = (kk < 512) ? hi : f2bf(v - bf2f(hi));
}
__global__ void prep_bt2(const float* __restrict__ Wih2, const float* __restrict__ Whh2,
                         u16* __restrict__ Bt2) {
  int idx = blockIdx.x * 256 + threadIdx.x;       // 2048*2048
  int n = idx >> 11, kk = idx & 2047;
  int r = (n & 3) * HID + (n >> 2);
  int k = kk & 1023;
  float v = (k < 512) ? Wih2[r * HID + k] : Whh2[r * HID + (k - 512)];
  u16 hi = f2bf(v);
  Bt2[idx] = (kk < 1024) ? hi : f2bf(v - bf2f(hi));
}
__global__ void prep_small(const float* __restrict__ b1, const float* __restrict__ b2,
                           const float* __restrict__ Wih1,
                           float* __restrict__ b1p, float* __restrict__ b2p,
                           float* __restrict__ w1p) {
  int n = blockIdx.x * 256 + threadIdx.x;
  if (n >= 2048) return;
  int r = (n & 3) * HID + (n >> 2);
  b1p[n] = b1[r];
  b2p[n] = b2[r];
  w1p[2 * n + 0] = Wih1[2 * r + 0];
  w1p[2 * n + 1] = Wih1[2 * r + 1];
}
__global__ void init_out(const float* __restrict__ bl, float* __restrict__ out) {
  int i = blockIdx.x * 256 + threadIdx.x;
  if (i < BATCH * OUTW) out[i] = bl[i & 1];
}

// ---------- fused gate-GEMM + LSTM cell (+ optional out-projection) ----------
// Named pointer fields only — NO runtime-indexed arrays (R2's scratch-spill bug).
struct GArgs {
  const u16* Ah0; const u16* Ah1;   // hi activation chunks ([1024][512] each)
  const u16* Al0; const u16* Al1;   // lo activation chunks
  const u16* Bt;  int bstride;      // bf16 weight panel
  const float* bias;                // reordered bias [2048]
  const float* xptr; int xstride;   // layer-1 input (2 floats/row)
  const float* wih;                 // reordered Wih1 [2048][2]
  float* Cst;                       // cell state [1024][512], RMW
  u16* Hh; u16* Hl;                 // output h hi/lo
  const float* wl;                  // Wl [2][512] original order
  float* oacc;                      // out + 2t (atomic accumulate)
};

// BM=BN=64, BK=128. LDS: A[64][136] + B[64][136] bf16 = 34816 B.
template <int NCH, bool HASX, bool PROJ>
__device__ __forceinline__ void run_gemm(const GArgs& a, int mt, int nt, char* smem) {
  u16* As = (u16*)smem;
  u16* Bs = (u16*)(smem + 64 * 136 * 2);

  const int tid = threadIdx.x;
  const int wid = tid >> 6, lane = tid & 63;
  const int wm = wid >> 1, wn = wid & 1;
  const int r0 = tid >> 4;           // 0..15
  const int sl = tid & 15;           // 16B slot in a 256B row

  f32x4 acc[2][2] = {};
  constexpr int TOT = NCH * 4;       // K-steps of 128

  uint4 pa[4], pb[4];
  // Compile-time-shaped chunk select (ternary chains -> s_cselect, stays in regs)
  auto loadT = [&](int ks) {
    int c = ks >> 2, k0 = (ks & 3) * 128;
    const u16* Ab; int boff;
    if (NCH == 3) {  // chunks {Ah0, Ah0, Al0} x B {hi, lo, hi}
      Ab = (c < 2) ? a.Ah0 : a.Al0;
      boff = (c == 1) ? 512 : 0;
    } else {         // chunks {Ah0,Ah1,Ah0,Ah1,Al0,Al1} x B {hi,hi,lo,lo,hi,hi}
      Ab = (c < 4) ? ((c & 1) ? a.Ah1 : a.Ah0) : ((c & 1) ? a.Ah1 : a.Ah0);
      Ab = (c < 4) ? Ab : ((c & 1) ? a.Al1 : a.Al0);
      boff = (c < 4) ? c * 512 : (c - 4) * 512;
    }
    const u16* Ap = Ab + (size_t)(mt * 64) * HID + k0 + sl * 8;
    const u16* Bp = a.Bt + (size_t)(nt * 64) * a.bstride + boff + k0 + sl * 8;
#pragma unroll
    for (int i = 0; i < 4; ++i) {
      pa[i] = *(const uint4*)(Ap + (size_t)(r0 + 16 * i) * HID);
      pb[i] = *(const uint4*)(Bp + (size_t)(r0 + 16 * i) * a.bstride);
    }
  };
  loadT(0);

  for (int ks = 0; ks < TOT; ++ks) {
    __syncthreads();                 // prev compute done, LDS free
#pragma unroll
    for (int i = 0; i < 4; ++i) {
      *(uint4*)(As + (r0 + 16 * i) * 136 + sl * 8) = pa[i];
      *(uint4*)(Bs + (r0 + 16 * i) * 136 + sl * 8) = pb[i];
    }
    __syncthreads();                 // LDS ready
    if (ks + 1 < TOT) loadT(ks + 1); // regs free after LDS store; hides latency under MFMA
#pragma unroll
    for (int kk = 0; kk < 4; ++kk) {
      const int ko = kk * 32 + (lane >> 4) * 8;
      bf16x8 a0 = *(const bf16x8*)(As + (wm * 32 +  0 + (lane & 15)) * 136 + ko);
      bf16x8 a1 = *(const bf16x8*)(As + (wm * 32 + 16 + (lane & 15)) * 136 + ko);
      bf16x8 b0 = *(const bf16x8*)(Bs + (wn * 32 +  0 + (lane & 15)) * 136 + ko);
      bf16x8 b1 = *(const bf16x8*)(Bs + (wn * 32 + 16 + (lane & 15)) * 136 + ko);
      acc[0][0] = __builtin_amdgcn_mfma_f32_16x16x32_bf16(a0, b0, acc[0][0], 0, 0, 0);
      acc[0][1] = __builtin_amdgcn_mfma_f32_16x16x32_bf16(a0, b1, acc[0][1], 0, 0, 0);
      acc[1][0] = __builtin_amdgcn_mfma_f32_16x16x32_bf16(a1, b0, acc[1][0], 0, 0, 0);
      acc[1][1] = __builtin_amdgcn_mfma_f32_16x16x32_bf16(a1, b1, acc[1][1], 0, 0, 0);
    }
  }

  // ---- epilogue ----
  __syncthreads();
  float* Cl = (float*)smem;                        // [64][65]
#pragma unroll
  for (int mi = 0; mi < 2; ++mi)
#pragma unroll
    for (int ni = 0; ni < 2; ++ni)
#pragma unroll
      for (int r = 0; r < 4; ++r) {
        int row = wm * 32 + mi * 16 + (lane >> 4) * 4 + r;
        int col = wn * 32 + ni * 16 + (lane & 15);
        Cl[row * 65 + col] = acc[mi][ni][r];
      }
  __syncthreads();

  const int mg0 = mt * 64;
  const int hg0 = nt * 16;
#pragma unroll
  for (int q = 0; q < 4; ++q) {
    int idx = q * 256 + tid;          // 64 rows x 16 h
    int m = idx >> 4, hl = idx & 15;
    int mg = mg0 + m, hg = hg0 + hl;
    int nb = hg * 4;
    float g0 = Cl[m * 65 + hl * 4 + 0] + a.bias[nb + 0];
    float g1 = Cl[m * 65 + hl * 4 + 1] + a.bias[nb + 1];
    float g2 = Cl[m * 65 + hl * 4 + 2] + a.bias[nb + 2];
    float g3 = Cl[m * 65 + hl * 4 + 3] + a.bias[nb + 3];
    if (HASX) {
      float x0 = a.xptr[(size_t)mg * a.xstride + 0];
      float x1 = a.xptr[(size_t)mg * a.xstride + 1];
      g0 += x0 * a.wih[(nb + 0) * 2] + x1 * a.wih[(nb + 0) * 2 + 1];
      g1 += x0 * a.wih[(nb + 1) * 2] + x1 * a.wih[(nb + 1) * 2 + 1];
      g2 += x0 * a.wih[(nb + 2) * 2] + x1 * a.wih[(nb + 2) * 2 + 1];
      g3 += x0 * a.wih[(nb + 3) * 2] + x1 * a.wih[(nb + 3) * 2 + 1];
    }
    float ig = sigm(g0), fg = sigm(g1), gg = tanh_fast(g2), og = sigm(g3);
    float cp = a.Cst[(size_t)mg * HID + hg];
    float cn = fg * cp + ig * gg;
    a.Cst[(size_t)mg * HID + hg] = cn;
    float hn = og * tanh_fast(cn);
    u16 hi = f2bf(hn);
    a.Hh[(size_t)mg * HID + hg] = hi;
    a.Hl[(size_t)mg * HID + hg] = f2bf(hn - bf2f(hi));
    if (PROJ) {                       // fused output projection
      float s0 = hn * a.wl[hg];
      float s1 = hn * a.wl[HID + hg];
      s0 += __shfl_down(s0, 8); s1 += __shfl_down(s1, 8);
      s0 += __shfl_down(s0, 4); s1 += __shfl_down(s1, 4);
      s0 += __shfl_down(s0, 2); s1 += __shfl_down(s1, 2);
      s0 += __shfl_down(s0, 1); s1 += __shfl_down(s1, 1);
      if (hl == 0) {
        unsafeAtomicAdd(&a.oacc[(size_t)mg * OUTW + 0], s0);
        unsafeAtomicAdd(&a.oacc[(size_t)mg * OUTW + 1], s1);
      }
    }
  }
}

// XCD-pinned tile mapping: xcd = bid&7 always owns nt in [xcd*4, xcd*4+4)
// -> each XCD keeps its 1.5 MB weight slice L2-resident across all 95 steps.
template <int NCH, bool HASX, bool PROJ>
__global__ __launch_bounds__(256, 2) void step_single(GArgs ga) {
  __shared__ __align__(16) char smem[34816];
  int bid = blockIdx.x;
  int x = bid & 7, j = bid >> 3;     // j in [0,64)
  int nt = x * 4 + (j & 3);
  int mt = j >> 2;
  run_gemm<NCH, HASX, PROJ>(ga, mt, nt, smem);
}

// grid 1024: j<64 -> L2(t) (+proj), j>=64 -> L1(t+1)  (independent GEMMs)
__global__ __launch_bounds__(256, 2) void step_fused(GArgs g2, GArgs g1) {
  __shared__ __align__(16) char smem[34816];
  int bid = blockIdx.x;
  int x = bid & 7, j = bid >> 3;     // j in [0,128)
  int jj = j & 63;
  int nt = x * 4 + (jj & 3);
  int mt = jj >> 2;
  if (j < 64) run_gemm<6, false, true>(g2, mt, nt, smem);
  else        run_gemm<3, true, false>(g1, mt, nt, smem);
}

// ---------- host ----------
extern "C" void kernel_launch(void* const* d_in, const int* in_sizes, int n_in,
                              void* d_out, int out_size, void* d_ws, size_t ws_size,
                              hipStream_t stream) {
  const float* x    = (const float*)d_in[0];
  const float* Wih1 = (const float*)d_in[1];
  const float* Whh1 = (const float*)d_in[2];
  const float* b1   = (const float*)d_in[3];
  const float* Wih2 = (const float*)d_in[4];
  const float* Whh2 = (const float*)d_in[5];
  const float* b2   = (const float*)d_in[6];
  const float* Wl   = (const float*)d_in[7];
  const float* bl   = (const float*)d_in[8];
  float* out = (float*)d_out;
  (void)in_sizes; (void)n_in; (void)out_size; (void)ws_size;

  char* p = (char*)d_ws;
  auto alloc = [&](size_t bytes) -> char* {
    char* r = p; p += (bytes + 255) & ~(size_t)255; return r;
  };
  u16* Bt1 = (u16*)alloc((size_t)2048 * 1024 * 2);   // 4 MB
  u16* Bt2 = (u16*)alloc((size_t)2048 * 2048 * 2);   // 8 MB
  char* state0 = p;
  u16* Hb[8];                                        // H1h[2],H1l[2],H2h[2],H2l[2]
  for (int i = 0; i < 8; ++i) Hb[i] = (u16*)alloc((size_t)BATCH * HID * 2);
  float* C1 = (float*)alloc((size_t)BATCH * HID * 4);
  float* C2 = (float*)alloc((size_t)BATCH * HID * 4);
  size_t state_bytes = (size_t)(p - state0);
  float* b1p = (float*)alloc(2048 * 4);
  float* b2p = (float*)alloc(2048 * 4);
  float* w1p = (float*)alloc(2048 * 2 * 4);

  hipMemsetAsync(state0, 0, state_bytes, stream);    // h,c = 0
  init_out<<<(BATCH * OUTW + 255) / 256, 256, 0, stream>>>(bl, out);
  prep_bt1<<<8192, 256, 0, stream>>>(Whh1, Bt1);
  prep_bt2<<<16384, 256, 0, stream>>>(Wih2, Whh2, Bt2);
  prep_small<<<8, 256, 0, stream>>>(b1, b2, Wih1, b1p, b2p, w1p);

  auto mkL1 = [&](int t) -> GArgs {
    int par = t & 1, prev = par ^ 1;
    GArgs a{};
    a.Ah0 = Hb[0 + prev]; a.Ah1 = nullptr;
    a.Al0 = Hb[2 + prev]; a.Al1 = nullptr;
    a.Bt = Bt1; a.bstride = 1024; a.bias = b1p;
    a.xptr = (t < T_OBS) ? (x + 2 * t) : (out + 2 * (t - 1));
    a.xstride = (t < T_OBS) ? (2 * T_OBS) : OUTW;
    a.wih = w1p; a.Cst = C1;
    a.Hh = Hb[0 + par]; a.Hl = Hb[2 + par];
    a.wl = nullptr; a.oacc = nullptr;
    return a;
  };
  auto mkL2 = [&](int t) -> GArgs {
    int par = t & 1, prev = par ^ 1;
    GArgs a{};
    a.Ah0 = Hb[0 + par];  a.Ah1 = Hb[4 + prev];
    a.Al0 = Hb[2 + par];  a.Al1 = Hb[6 + prev];
    a.Bt = Bt2; a.bstride = 2048; a.bias = b2p;
    a.xptr = nullptr; a.xstride = 0; a.wih = nullptr;
    a.Cst = C2;
    a.Hh = Hb[4 + par]; a.Hl = Hb[6 + par];
    a.wl = Wl; a.oacc = out + 2 * t;
    return a;
  };

  // step 0 layer 1
  step_single<3, true, false><<<512, 256, 0, stream>>>(mkL1(0));
  // observed steps: L2(t) and L1(t+1) are independent -> one 1024-WG dispatch
  for (int t = 0; t < T_OBS - 1; ++t)
    step_fused<<<1024, 256, 0, stream>>>(mkL2(t), mkL1(t + 1));
  // last observed L2 (writes out[63])
  step_single<6, false, true><<<512, 256, 0, stream>>>(mkL2(T_OBS - 1));
  // future steps: strict chain L1 -> L2(+proj) -> L1 ...
  for (int t = T_OBS; t < NSTEPS; ++t) {
    step_single<3, true, false><<<512, 256, 0, stream>>>(mkL1(t));
    step_single<6, false, true><<<512, 256, 0, stream>>>(mkL2(t));
  }
}

// Round 4
// 4002.294 us; speedup vs baseline: 3.9203x; 3.8080x over previous
//
#include <hip/hip_runtime.h>
#include <cstdint>
#include <cstddef>

typedef unsigned short u16;
typedef __bf16 bf16_t;
typedef bf16_t bf16x8 __attribute__((ext_vector_type(8)));
typedef float f32x4 __attribute__((ext_vector_type(4)));

static constexpr int HID    = 512;
static constexpr int BATCH  = 1024;
static constexpr int NSTEPS = 95;   // T + future - 1 = 64 + 31
static constexpr int T_OBS  = 64;
static constexpr int OUTW   = 190;  // 2 * NSTEPS

// ---------- helpers ----------
__device__ __forceinline__ u16 f2bf(float x) {
  union { float f; uint32_t u; } c; c.f = x;
  uint32_t r = c.u + 0x7fffu + ((c.u >> 16) & 1u);   // RNE
  return (u16)(r >> 16);
}
__device__ __forceinline__ float bf2f(u16 h) {
  union { uint32_t u; float f; } c; c.u = ((uint32_t)h) << 16;
  return c.f;
}
__device__ __forceinline__ float sigm(float x) { return 1.f / (1.f + __expf(-x)); }
__device__ __forceinline__ float tanh_fast(float x) {
  float ax = fabsf(x);
  float t  = __expf(-2.f * ax);
  float r  = (1.f - t) / (1.f + t);
  return x < 0.f ? -r : r;
}

// ---------- weight prep (gate-interleaved column order) ----------
// col n = 4*h + g  <->  original row r = g*512 + h
__global__ void prep_bt1(const float* __restrict__ Whh1, u16* __restrict__ Bt1) {
  int idx = blockIdx.x * 256 + threadIdx.x;       // 2048*1024
  int n = idx >> 10, kk = idx & 1023;
  int r = (n & 3) * HID + (n >> 2);
  int k = kk & 511;
  float v = Whh1[r * HID + k];
  u16 hi = f2bf(v);
  Bt1[idx] = (kk < 512) ? hi : f2bf(v - bf2f(hi));
}
__global__ void prep_bt2(const float* __restrict__ Wih2, const float* __restrict__ Whh2,
                         u16* __restrict__ Bt2) {
  int idx = blockIdx.x * 256 + threadIdx.x;       // 2048*2048
  int n = idx >> 11, kk = idx & 2047;
  int r = (n & 3) * HID + (n >> 2);
  int k = kk & 1023;
  float v = (k < 512) ? Wih2[r * HID + k] : Whh2[r * HID + (k - 512)];
  u16 hi = f2bf(v);
  Bt2[idx] = (kk < 1024) ? hi : f2bf(v - bf2f(hi));
}
__global__ void prep_small(const float* __restrict__ b1, const float* __restrict__ b2,
                           const float* __restrict__ Wih1,
                           float* __restrict__ b1p, float* __restrict__ b2p,
                           float* __restrict__ w1p) {
  int n = blockIdx.x * 256 + threadIdx.x;
  if (n >= 2048) return;
  int r = (n & 3) * HID + (n >> 2);
  b1p[n] = b1[r];
  b2p[n] = b2[r];
  w1p[2 * n + 0] = Wih1[2 * r + 0];
  w1p[2 * n + 1] = Wih1[2 * r + 1];
}
__global__ void init_out(const float* __restrict__ bl, float* __restrict__ out) {
  int i = blockIdx.x * 256 + threadIdx.x;
  if (i < BATCH * OUTW) out[i] = bl[i & 1];
}

// ---------- fused gate-GEMM + LSTM cell (+ optional out-projection) ----------
struct GArgs {
  const u16* Ah0; const u16* Ah1;   // hi activation chunks ([1024][512] each)
  const u16* Al0; const u16* Al1;   // lo activation chunks
  const u16* Bt;  int bstride;      // bf16 weight panel
  const float* bias;                // reordered bias [2048]
  const float* xptr; int xstride;   // layer-1 input (2 floats/row)
  const float* wih;                 // reordered Wih1 [2048][2]
  float* Cst;                       // cell state [1024][512], RMW
  u16* Hh; u16* Hl;                 // output h hi/lo
  const float* wl;                  // Wl [2][512] original order
  float* oacc;                      // out + 2t (atomic accumulate)
};

// Load one BK=128 K-step into 8 NAMED uint4 scalars. No arrays, no lambda
// (R2/R3 lesson: reference-captured local arrays -> scratch, 400MB spill traffic).
#define LOADT(ks)                                                              \
  {                                                                            \
    const int c_ = (ks) >> 2, k0_ = ((ks) & 3) * 128;                          \
    const u16* Ab_; int boff_;                                                 \
    if (NCH == 3) {  /* chunks {Ah0, Ah0, Al0} x B {hi, lo, hi} */             \
      Ab_ = (c_ < 2) ? Ah0 : Al0;                                              \
      boff_ = (c_ == 1) ? 512 : 0;                                             \
    } else {         /* {Ah0,Ah1,Ah0,Ah1,Al0,Al1} x B {hi,hi,lo,lo,hi,hi} */   \
      const u16* Abh_ = (c_ & 1) ? Ah1 : Ah0;                                  \
      const u16* Abl_ = (c_ & 1) ? Al1 : Al0;                                  \
      Ab_ = (c_ < 4) ? Abh_ : Abl_;                                            \
      boff_ = (c_ < 4) ? c_ * 512 : (c_ - 4) * 512;                            \
    }                                                                          \
    const u16* Ap_ = Ab_ + (size_t)(mt * 64) * HID + k0_ + sl * 8;             \
    const u16* Bp_ = Bt + (size_t)(nt * 64) * bstride + boff_ + k0_ + sl * 8;  \
    pa0 = *(const uint4*)(Ap_ + (size_t)(r0 +  0) * HID);                      \
    pa1 = *(const uint4*)(Ap_ + (size_t)(r0 + 16) * HID);                      \
    pa2 = *(const uint4*)(Ap_ + (size_t)(r0 + 32) * HID);                      \
    pa3 = *(const uint4*)(Ap_ + (size_t)(r0 + 48) * HID);                      \
    pb0 = *(const uint4*)(Bp_ + (size_t)(r0 +  0) * bstride);                  \
    pb1 = *(const uint4*)(Bp_ + (size_t)(r0 + 16) * bstride);                  \
    pb2 = *(const uint4*)(Bp_ + (size_t)(r0 + 32) * bstride);                  \
    pb3 = *(const uint4*)(Bp_ + (size_t)(r0 + 48) * bstride);                  \
  }

// BM=BN=64, BK=128. LDS: A[64][136] + B[64][136] bf16 = 34816 B.
template <int NCH, bool HASX, bool PROJ>
__device__ __forceinline__ void run_gemm(const GArgs& g, int mt, int nt, char* smem) {
  // hoist all struct fields into named locals (no re-reads through the ref)
  const u16* const Ah0 = g.Ah0;  const u16* const Ah1 = g.Ah1;
  const u16* const Al0 = g.Al0;  const u16* const Al1 = g.Al1;
  const u16* const Bt  = g.Bt;   const int bstride = g.bstride;
  const float* const bias = g.bias;
  const float* const xptr = g.xptr; const int xstride = g.xstride;
  const float* const wih  = g.wih;
  float* const Cst = g.Cst;
  u16* const Hh = g.Hh;  u16* const Hl = g.Hl;
  const float* const wl = g.wl;
  float* const oacc = g.oacc;

  u16* As = (u16*)smem;
  u16* Bs = (u16*)(smem + 64 * 136 * 2);

  const int tid = threadIdx.x;
  const int wid = tid >> 6, lane = tid & 63;
  const int wm = wid >> 1, wn = wid & 1;
  const int r0 = tid >> 4;           // 0..15
  const int sl = tid & 15;           // 16B slot in a 256B row

  f32x4 acc00 = {}, acc01 = {}, acc10 = {}, acc11 = {};
  constexpr int TOT = NCH * 4;       // K-steps of 128

  uint4 pa0, pa1, pa2, pa3, pb0, pb1, pb2, pb3;
  LOADT(0);

  for (int ks = 0; ks < TOT; ++ks) {
    __syncthreads();                 // prev compute done, LDS free
    *(uint4*)(As + (r0 +  0) * 136 + sl * 8) = pa0;
    *(uint4*)(As + (r0 + 16) * 136 + sl * 8) = pa1;
    *(uint4*)(As + (r0 + 32) * 136 + sl * 8) = pa2;
    *(uint4*)(As + (r0 + 48) * 136 + sl * 8) = pa3;
    *(uint4*)(Bs + (r0 +  0) * 136 + sl * 8) = pb0;
    *(uint4*)(Bs + (r0 + 16) * 136 + sl * 8) = pb1;
    *(uint4*)(Bs + (r0 + 32) * 136 + sl * 8) = pb2;
    *(uint4*)(Bs + (r0 + 48) * 136 + sl * 8) = pb3;
    __syncthreads();                 // LDS ready
    if (ks + 1 < TOT) LOADT(ks + 1); // prefetch hides under MFMA
#pragma unroll
    for (int kk = 0; kk < 4; ++kk) {
      const int ko = kk * 32 + (lane >> 4) * 8;
      bf16x8 a0 = *(const bf16x8*)(As + (wm * 32 +  0 + (lane & 15)) * 136 + ko);
      bf16x8 a1 = *(const bf16x8*)(As + (wm * 32 + 16 + (lane & 15)) * 136 + ko);
      bf16x8 b0 = *(const bf16x8*)(Bs + (wn * 32 +  0 + (lane & 15)) * 136 + ko);
      bf16x8 b1 = *(const bf16x8*)(Bs + (wn * 32 + 16 + (lane & 15)) * 136 + ko);
      acc00 = __builtin_amdgcn_mfma_f32_16x16x32_bf16(a0, b0, acc00, 0, 0, 0);
      acc01 = __builtin_amdgcn_mfma_f32_16x16x32_bf16(a0, b1, acc01, 0, 0, 0);
      acc10 = __builtin_amdgcn_mfma_f32_16x16x32_bf16(a1, b0, acc10, 0, 0, 0);
      acc11 = __builtin_amdgcn_mfma_f32_16x16x32_bf16(a1, b1, acc11, 0, 0, 0);
    }
  }

  // ---- epilogue ----
  __syncthreads();
  float* Cl = (float*)smem;                        // [64][65]
  {
    const int rb = (lane >> 4) * 4;
    const int cb = lane & 15;
#pragma unroll
    for (int r = 0; r < 4; ++r) {
      Cl[(wm * 32 +  0 + rb + r) * 65 + wn * 32 +  0 + cb] = acc00[r];
      Cl[(wm * 32 +  0 + rb + r) * 65 + wn * 32 + 16 + cb] = acc01[r];
      Cl[(wm * 32 + 16 + rb + r) * 65 + wn * 32 +  0 + cb] = acc10[r];
      Cl[(wm * 32 + 16 + rb + r) * 65 + wn * 32 + 16 + cb] = acc11[r];
    }
  }
  __syncthreads();

  const int mg0 = mt * 64;
  const int hg0 = nt * 16;
#pragma unroll
  for (int q = 0; q < 4; ++q) {
    int idx = q * 256 + tid;          // 64 rows x 16 h
    int m = idx >> 4, hl = idx & 15;
    int mg = mg0 + m, hg = hg0 + hl;
    int nb = hg * 4;
    float g0 = Cl[m * 65 + hl * 4 + 0] + bias[nb + 0];
    float g1 = Cl[m * 65 + hl * 4 + 1] + bias[nb + 1];
    float g2 = Cl[m * 65 + hl * 4 + 2] + bias[nb + 2];
    float g3 = Cl[m * 65 + hl * 4 + 3] + bias[nb + 3];
    if (HASX) {
      float x0 = xptr[(size_t)mg * xstride + 0];
      float x1 = xptr[(size_t)mg * xstride + 1];
      g0 += x0 * wih[(nb + 0) * 2] + x1 * wih[(nb + 0) * 2 + 1];
      g1 += x0 * wih[(nb + 1) * 2] + x1 * wih[(nb + 1) * 2 + 1];
      g2 += x0 * wih[(nb + 2) * 2] + x1 * wih[(nb + 2) * 2 + 1];
      g3 += x0 * wih[(nb + 3) * 2] + x1 * wih[(nb + 3) * 2 + 1];
    }
    float ig = sigm(g0), fg = sigm(g1), gg = tanh_fast(g2), og = sigm(g3);
    float cp = Cst[(size_t)mg * HID + hg];
    float cn = fg * cp + ig * gg;
    Cst[(size_t)mg * HID + hg] = cn;
    float hn = og * tanh_fast(cn);
    u16 hi = f2bf(hn);
    Hh[(size_t)mg * HID + hg] = hi;
    Hl[(size_t)mg * HID + hg] = f2bf(hn - bf2f(hi));
    if (PROJ) {                       // fused output projection
      float s0 = hn * wl[hg];
      float s1 = hn * wl[HID + hg];
      s0 += __shfl_down(s0, 8); s1 += __shfl_down(s1, 8);
      s0 += __shfl_down(s0, 4); s1 += __shfl_down(s1, 4);
      s0 += __shfl_down(s0, 2); s1 += __shfl_down(s1, 2);
      s0 += __shfl_down(s0, 1); s1 += __shfl_down(s1, 1);
      if (hl == 0) {
        unsafeAtomicAdd(&oacc[(size_t)mg * OUTW + 0], s0);
        unsafeAtomicAdd(&oacc[(size_t)mg * OUTW + 1], s1);
      }
    }
  }
}

// XCD-pinned tile mapping: xcd = bid&7 always owns nt in [xcd*4, xcd*4+4)
// -> each XCD keeps its weight slice L2-resident across all 95 steps.
template <int NCH, bool HASX, bool PROJ>
__global__ __launch_bounds__(256, 2) void step_single(GArgs ga) {
  __shared__ __align__(16) char smem[34816];
  int bid = blockIdx.x;
  int x = bid & 7, j = bid >> 3;     // j in [0,64)
  int nt = x * 4 + (j & 3);
  int mt = j >> 2;
  run_gemm<NCH, HASX, PROJ>(ga, mt, nt, smem);
}

// grid 1024: j<64 -> L2(t) (+proj), j>=64 -> L1(t+1)  (independent GEMMs)
__global__ __launch_bounds__(256, 2) void step_fused(GArgs g2, GArgs g1) {
  __shared__ __align__(16) char smem[34816];
  int bid = blockIdx.x;
  int x = bid & 7, j = bid >> 3;     // j in [0,128)
  int jj = j & 63;
  int nt = x * 4 + (jj & 3);
  int mt = jj >> 2;
  if (j < 64) run_gemm<6, false, true>(g2, mt, nt, smem);
  else        run_gemm<3, true, false>(g1, mt, nt, smem);
}

// ---------- host ----------
extern "C" void kernel_launch(void* const* d_in, const int* in_sizes, int n_in,
                              void* d_out, int out_size, void* d_ws, size_t ws_size,
                              hipStream_t stream) {
  const float* x    = (const float*)d_in[0];
  const float* Wih1 = (const float*)d_in[1];
  const float* Whh1 = (const float*)d_in[2];
  const float* b1   = (const float*)d_in[3];
  const float* Wih2 = (const float*)d_in[4];
  const float* Whh2 = (const float*)d_in[5];
  const float* b2   = (const float*)d_in[6];
  const float* Wl   = (const float*)d_in[7];
  const float* bl   = (const float*)d_in[8];
  float* out = (float*)d_out;
  (void)in_sizes; (void)n_in; (void)out_size; (void)ws_size;

  char* p = (char*)d_ws;
  auto alloc = [&](size_t bytes) -> char* {
    char* r = p; p += (bytes + 255) & ~(size_t)255; return r;
  };
  u16* Bt1 = (u16*)alloc((size_t)2048 * 1024 * 2);   // 4 MB
  u16* Bt2 = (u16*)alloc((size_t)2048 * 2048 * 2);   // 8 MB
  char* state0 = p;
  u16* Hb[8];                                        // H1h[2],H1l[2],H2h[2],H2l[2]
  for (int i = 0; i < 8; ++i) Hb[i] = (u16*)alloc((size_t)BATCH * HID * 2);
  float* C1 = (float*)alloc((size_t)BATCH * HID * 4);
  float* C2 = (float*)alloc((size_t)BATCH * HID * 4);
  size_t state_bytes = (size_t)(p - state0);
  float* b1p = (float*)alloc(2048 * 4);
  float* b2p = (float*)alloc(2048 * 4);
  float* w1p = (float*)alloc(2048 * 2 * 4);

  hipMemsetAsync(state0, 0, state_bytes, stream);    // h,c = 0
  init_out<<<(BATCH * OUTW + 255) / 256, 256, 0, stream>>>(bl, out);
  prep_bt1<<<8192, 256, 0, stream>>>(Whh1, Bt1);
  prep_bt2<<<16384, 256, 0, stream>>>(Wih2, Whh2, Bt2);
  prep_small<<<8, 256, 0, stream>>>(b1, b2, Wih1, b1p, b2p, w1p);

  auto mkL1 = [&](int t) -> GArgs {
    int par = t & 1, prev = par ^ 1;
    GArgs a{};
    a.Ah0 = Hb[0 + prev]; a.Ah1 = nullptr;
    a.Al0 = Hb[2 + prev]; a.Al1 = nullptr;
    a.Bt = Bt1; a.bstride = 1024; a.bias = b1p;
    a.xptr = (t < T_OBS) ? (x + 2 * t) : (out + 2 * (t - 1));
    a.xstride = (t < T_OBS) ? (2 * T_OBS) : OUTW;
    a.wih = w1p; a.Cst = C1;
    a.Hh = Hb[0 + par]; a.Hl = Hb[2 + par];
    a.wl = nullptr; a.oacc = nullptr;
    return a;
  };
  auto mkL2 = [&](int t) -> GArgs {
    int par = t & 1, prev = par ^ 1;
    GArgs a{};
    a.Ah0 = Hb[0 + par];  a.Ah1 = Hb[4 + prev];
    a.Al0 = Hb[2 + par];  a.Al1 = Hb[6 + prev];
    a.Bt = Bt2; a.bstride = 2048; a.bias = b2p;
    a.xptr = nullptr; a.xstride = 0; a.wih = nullptr;
    a.Cst = C2;
    a.Hh = Hb[4 + par]; a.Hl = Hb[6 + par];
    a.wl = Wl; a.oacc = out + 2 * t;
    return a;
  };

  // step 0 layer 1
  step_single<3, true, false><<<512, 256, 0, stream>>>(mkL1(0));
  // observed steps: L2(t) and L1(t+1) are independent -> one 1024-WG dispatch
  for (int t = 0; t < T_OBS - 1; ++t)
    step_fused<<<1024, 256, 0, stream>>>(mkL2(t), mkL1(t + 1));
  // last observed L2 (writes out[63])
  step_single<6, false, true><<<512, 256, 0, stream>>>(mkL2(T_OBS - 1));
  // future steps: strict chain L1 -> L2(+proj) -> L1 ...
  for (int t = T_OBS; t < NSTEPS; ++t) {
    step_single<3, true, false><<<512, 256, 0, stream>>>(mkL1(t));
    step_single<6, false, true><<<512, 256, 0, stream>>>(mkL2(t));
  }
}